// Round 5
// baseline (800.672 us; speedup 1.0000x reference)
//
#include <hip/hip_runtime.h>

#define ALPHA_F 0.1f
#define EPS_F   1e-5f

typedef __bf16 bf16_t;
typedef __bf16 bf16x8 __attribute__((ext_vector_type(8)));
typedef float  f32x4  __attribute__((ext_vector_type(4)));
typedef unsigned short u16x8 __attribute__((ext_vector_type(8)));

// padded count per node: self-loop + edges, rounded up to multiple of 8
__device__ __forceinline__ int pad_cnt(int d) { return (d + 8) & ~7; }

// ---------------------------------------------------------------------------
// W [K x 128] fp32  ->  Wt_hi/Wt_lo [128 x K] bf16 (transposed, hi/lo split)
// ---------------------------------------------------------------------------
__global__ void convert_wt(const float* __restrict__ W,
                           bf16_t* __restrict__ hi, bf16_t* __restrict__ lo, int K)
{
    int idx = blockIdx.x * 256 + threadIdx.x;
    if (idx < K * 128) {
        int k = idx >> 7, n = idx & 127;
        float f  = W[idx];
        bf16_t h = (bf16_t)f;
        hi[(size_t)n * K + k] = h;
        lo[(size_t)n * K + k] = (bf16_t)(f - (float)h);
    }
}

// ---------------------------------------------------------------------------
// out[M,128] = BN( act(A[M,K] @ W[K,128] + bias) ), MFMA bf16x3 (near-fp32).
// ---------------------------------------------------------------------------
__global__ __launch_bounds__(128) void gemm_mfma_bn(
    const float* __restrict__ A,
    const bf16_t* __restrict__ Wthi, const bf16_t* __restrict__ Wtlo,  // [128][K]
    const float* __restrict__ bias,
    const float* __restrict__ gamma, const float* __restrict__ beta,
    const float* __restrict__ mean,  const float* __restrict__ var,
    float* __restrict__ out, int M, int K, int do_relu)
{
    __shared__ __align__(16) unsigned short WH[128][40];
    __shared__ __align__(16) unsigned short WL[128][40];

    const int t   = threadIdx.x;       // 0..127
    const int w   = t >> 6;            // wave 0..1
    const int l   = t & 63;
    const int l15 = l & 15;
    const int lk  = l >> 4;            // k-group 0..3
    const int bm  = blockIdx.x * 64;

    f32x4 acc[2][8];
#pragma unroll
    for (int m = 0; m < 2; ++m)
#pragma unroll
        for (int f = 0; f < 8; ++f) acc[m][f] = (f32x4){0.f, 0.f, 0.f, 0.f};

    for (int k0 = 0; k0 < K; k0 += 32) {
        f32x4 x0[2], x1[2];
#pragma unroll
        for (int m = 0; m < 2; ++m) {
            int r = bm + w * 32 + m * 16 + l15;
            x0[m] = (f32x4){0.f, 0.f, 0.f, 0.f};
            x1[m] = x0[m];
            if (r < M) {
                const float* ap = A + (size_t)r * K + k0 + lk * 8;
                x0[m] = *(const f32x4*)ap;
                x1[m] = *(const f32x4*)(ap + 4);
            }
        }
        {
            const bf16_t* gh = Wthi + (size_t)t * K + k0;
            const bf16_t* gl = Wtlo + (size_t)t * K + k0;
#pragma unroll
            for (int c = 0; c < 4; ++c) {
                *(u16x8*)&WH[t][c * 8] = *(const u16x8*)(gh + c * 8);
                *(u16x8*)&WL[t][c * 8] = *(const u16x8*)(gl + c * 8);
            }
        }
        __syncthreads();

        bf16x8 ahi[2], alo[2];
#pragma unroll
        for (int m = 0; m < 2; ++m) {
#pragma unroll
            for (int j = 0; j < 4; ++j) {
                float f0 = x0[m][j];
                bf16_t h0 = (bf16_t)f0;
                ahi[m][j] = h0;
                alo[m][j] = (bf16_t)(f0 - (float)h0);
                float f1 = x1[m][j];
                bf16_t h1 = (bf16_t)f1;
                ahi[m][4 + j] = h1;
                alo[m][4 + j] = (bf16_t)(f1 - (float)h1);
            }
        }
#pragma unroll
        for (int f = 0; f < 8; ++f) {
            u16x8 uh = *(const u16x8*)&WH[f * 16 + l15][lk * 8];
            u16x8 ul = *(const u16x8*)&WL[f * 16 + l15][lk * 8];
            bf16x8 wh = __builtin_bit_cast(bf16x8, uh);
            bf16x8 wl = __builtin_bit_cast(bf16x8, ul);
#pragma unroll
            for (int m = 0; m < 2; ++m) {
                acc[m][f] = __builtin_amdgcn_mfma_f32_16x16x32_bf16(ahi[m], wh, acc[m][f], 0, 0, 0);
                acc[m][f] = __builtin_amdgcn_mfma_f32_16x16x32_bf16(alo[m], wh, acc[m][f], 0, 0, 0);
                acc[m][f] = __builtin_amdgcn_mfma_f32_16x16x32_bf16(ahi[m], wl, acc[m][f], 0, 0, 0);
            }
        }
        __syncthreads();
    }

#pragma unroll
    for (int f = 0; f < 8; ++f) {
        int col  = f * 16 + l15;
        float s  = gamma[col] * rsqrtf(var[col] + EPS_F);
        float sh = beta[col] - mean[col] * s;
        float bb = bias[col];
#pragma unroll
        for (int m = 0; m < 2; ++m) {
            int rbase = bm + w * 32 + m * 16 + lk * 4;
#pragma unroll
            for (int rr = 0; rr < 4; ++rr) {
                int rg = rbase + rr;
                if (rg < M) {
                    float v = acc[m][f][rr] + bb;
                    if (do_relu) v = fmaxf(v, 0.f);
                    out[(size_t)rg * 128 + col] = v * s + sh;
                }
            }
        }
    }
}

// ---------------------------------------------------------------------------
// Graph preprocessing (per launch)
// ---------------------------------------------------------------------------
__global__ void count_deg(const int* __restrict__ dst, int E, int* __restrict__ deg)
{
    int e = blockIdx.x * 256 + threadIdx.x;
    if (e < E) atomicAdd(&deg[dst[e]], 1);
}

// k1: per-block (1024 nodes) sum of padded counts
__global__ __launch_bounds__(256) void scan_block_sums(
    const int* __restrict__ deg, int* __restrict__ bsum, int N)
{
    __shared__ int sh[256];
    const int t  = threadIdx.x;
    const int i0 = blockIdx.x * 1024 + t * 4;
    int s = 0;
    if (i0 + 3 < N) {
        int4 d4 = *(const int4*)(deg + i0);
        s = pad_cnt(d4.x) + pad_cnt(d4.y) + pad_cnt(d4.z) + pad_cnt(d4.w);
    } else {
#pragma unroll
        for (int j = 0; j < 4; ++j)
            if (i0 + j < N) s += pad_cnt(deg[i0 + j]);
    }
    sh[t] = s;
    __syncthreads();
#pragma unroll
    for (int d = 128; d > 0; d >>= 1) {
        if (t < d) sh[t] += sh[t + d];
        __syncthreads();
    }
    if (t == 0) bsum[blockIdx.x] = sh[0];
}

// k2: per-block base (reduce of prior bsum) + local Hillis-Steele -> offs/cursor
__global__ __launch_bounds__(256) void scan_offsets(
    const int* __restrict__ deg, const int* __restrict__ bsum,
    int* __restrict__ offs, int* __restrict__ cursor, int N, int B)
{
    __shared__ int sh[256];
    __shared__ int sbase;
    const int b = blockIdx.x, t = threadIdx.x;

    int v = (t < b && t < B) ? bsum[t] : 0;   // B <= 256
    sh[t] = v;
    __syncthreads();
#pragma unroll
    for (int d = 128; d > 0; d >>= 1) {
        if (t < d) sh[t] += sh[t + d];
        __syncthreads();
    }
    if (t == 0) sbase = sh[0];
    __syncthreads();

    const int i0 = b * 1024 + t * 4;
    int c[4], s = 0;
#pragma unroll
    for (int j = 0; j < 4; ++j) {
        int i = i0 + j;
        c[j] = (i < N) ? pad_cnt(deg[i]) : 0;
        s += c[j];
    }
    sh[t] = s;
    __syncthreads();
    for (int d = 1; d < 256; d <<= 1) {
        int o = (t >= d) ? sh[t - d] : 0;
        __syncthreads();
        sh[t] += o;
        __syncthreads();
    }
    int run = sbase + sh[t] - s;   // exclusive prefix
#pragma unroll
    for (int j = 0; j < 4; ++j) {
        int i = i0 + j;
        if (i < N) {
            offs[i]   = run;
            cursor[i] = run;
            run += c[j];
        }
    }
    if (b == B - 1 && t == 255) offs[N] = run;
}

__global__ void compute_dinv(const int* __restrict__ deg, float* __restrict__ dinv, int N)
{
    int i = blockIdx.x * 256 + threadIdx.x;
    if (i < N) dinv[i] = rsqrtf((float)(deg[i] + 1));  // +1 self loop
}

__global__ void scatter_csr(const int* __restrict__ src, const int* __restrict__ dst,
                            int E, const float* __restrict__ dinv,
                            int* __restrict__ cursor,
                            int* __restrict__ csr_src, float* __restrict__ csr_val)
{
    int e = blockIdx.x * 256 + threadIdx.x;
    if (e < E) {
        int s = src[e], d = dst[e];
        int pos = atomicAdd(&cursor[d], 1);
        csr_src[pos] = s;
        csr_val[pos] = dinv[s] * dinv[d];
    }
}

__global__ void fill_self_pad(const int* __restrict__ offs, const int* __restrict__ deg,
                              const float* __restrict__ dinv,
                              int* __restrict__ csr_src, float* __restrict__ csr_val, int N)
{
    int i = blockIdx.x * 256 + threadIdx.x;
    if (i < N) {
        int base = offs[i], d = deg[i], end = offs[i + 1];
        float di = dinv[i];
        csr_src[base + d] = i;
        csr_val[base + d] = di * di;
        for (int p = base + d + 1; p < end; ++p) {
            csr_src[p] = i;
            csr_val[p] = 0.f;
        }
    }
}

// ---------------------------------------------------------------------------
// One APPNP step: nxt = (1-a)*(A_hat @ cur) + a*h0.  One wave per node,
// 64 lanes x float2 = 128 feats. Segments padded to x8 -> tail-free unroll-8,
// 8 gathers in flight per wave. CSR metadata via scalar loads (uniform addr).
// ---------------------------------------------------------------------------
__global__ __launch_bounds__(256) void appnp_step(
    const float* __restrict__ cur, const float* __restrict__ h0,
    const int* __restrict__ offs,
    const int* __restrict__ csr_src, const float* __restrict__ csr_val,
    float* __restrict__ nxt, int N)
{
    int wv = (int)((blockIdx.x * 256u + threadIdx.x) >> 6);
    if (wv >= N) return;
    const int i    = __builtin_amdgcn_readfirstlane(wv);
    const int lane = (int)(threadIdx.x & 63u);
    const int c    = lane * 2;

    int e   = offs[i];
    int end = offs[i + 1];
    float ax = 0.f, ay = 0.f;
    for (; e < end; e += 8) {
        int4   sa = *(const int4*)(csr_src + e);
        int4   sb = *(const int4*)(csr_src + e + 4);
        float4 wa = *(const float4*)(csr_val + e);
        float4 wb = *(const float4*)(csr_val + e + 4);
        float2 v0 = *(const float2*)(cur + (size_t)sa.x * 128 + c);
        float2 v1 = *(const float2*)(cur + (size_t)sa.y * 128 + c);
        float2 v2 = *(const float2*)(cur + (size_t)sa.z * 128 + c);
        float2 v3 = *(const float2*)(cur + (size_t)sa.w * 128 + c);
        float2 v4 = *(const float2*)(cur + (size_t)sb.x * 128 + c);
        float2 v5 = *(const float2*)(cur + (size_t)sb.y * 128 + c);
        float2 v6 = *(const float2*)(cur + (size_t)sb.z * 128 + c);
        float2 v7 = *(const float2*)(cur + (size_t)sb.w * 128 + c);
        ax = fmaf(wa.x, v0.x, ax); ay = fmaf(wa.x, v0.y, ay);
        ax = fmaf(wa.y, v1.x, ax); ay = fmaf(wa.y, v1.y, ay);
        ax = fmaf(wa.z, v2.x, ax); ay = fmaf(wa.z, v2.y, ay);
        ax = fmaf(wa.w, v3.x, ax); ay = fmaf(wa.w, v3.y, ay);
        ax = fmaf(wb.x, v4.x, ax); ay = fmaf(wb.x, v4.y, ay);
        ax = fmaf(wb.y, v5.x, ax); ay = fmaf(wb.y, v5.y, ay);
        ax = fmaf(wb.z, v6.x, ax); ay = fmaf(wb.z, v6.y, ay);
        ax = fmaf(wb.w, v7.x, ax); ay = fmaf(wb.w, v7.y, ay);
    }

    float2 h0v = *(const float2*)(h0 + (size_t)i * 128 + c);
    float2 o;
    o.x = ALPHA_F * h0v.x + (1.f - ALPHA_F) * ax;
    o.y = ALPHA_F * h0v.y + (1.f - ALPHA_F) * ay;
    *(float2*)(nxt + (size_t)i * 128 + c) = o;
}

// ---------------------------------------------------------------------------
static inline size_t align_up(size_t x) { return (x + 255) & ~(size_t)255; }

extern "C" void kernel_launch(void* const* d_in, const int* in_sizes, int n_in,
                              void* d_out, int out_size, void* d_ws, size_t ws_size,
                              hipStream_t stream)
{
    const float* x   = (const float*)d_in[0];
    const int*   ei  = (const int*)d_in[1];
    const float* W1  = (const float*)d_in[2];
    const float* b1  = (const float*)d_in[3];
    const float* g1  = (const float*)d_in[4];
    const float* be1 = (const float*)d_in[5];
    const float* m1  = (const float*)d_in[6];
    const float* v1  = (const float*)d_in[7];
    const float* W2  = (const float*)d_in[8];
    const float* b2  = (const float*)d_in[9];
    const float* g2  = (const float*)d_in[10];
    const float* be2 = (const float*)d_in[11];
    const float* m2  = (const float*)d_in[12];
    const float* v2  = (const float*)d_in[13];

    const int N = in_sizes[0] / 512;   // 50000
    const int E = in_sizes[1] / 2;     // 800000
    const int* src = ei;
    const int* dst = ei + E;
    const int CSR_CAP = E + 8 * N;
    const int NB = (N + 1023) / 1024;  // scan blocks (49)

    char* ws = (char*)d_ws;
    size_t off = 0;
    float*  h0   = (float*)(ws + off);  off += align_up((size_t)N * 128 * 4);
    float*  hA   = (float*)(ws + off);  off += align_up((size_t)N * 128 * 4);
    int*    deg  = (int*)(ws + off);    off += align_up((size_t)N * 4);
    float*  dinv = (float*)(ws + off);  off += align_up((size_t)N * 4);
    int*    offs = (int*)(ws + off);    off += align_up((size_t)(N + 1) * 4);
    int*    curs = (int*)(ws + off);    off += align_up((size_t)N * 4);
    int*    bsum = (int*)(ws + off);    off += align_up((size_t)256 * 4);
    int*    csrs = (int*)(ws + off);    off += align_up((size_t)CSR_CAP * 4);
    float*  csrv = (float*)(ws + off);  off += align_up((size_t)CSR_CAP * 4);
    bf16_t* w1h  = (bf16_t*)(ws + off); off += align_up((size_t)512 * 128 * 2);
    bf16_t* w1l  = (bf16_t*)(ws + off); off += align_up((size_t)512 * 128 * 2);
    bf16_t* w2h  = (bf16_t*)(ws + off); off += align_up((size_t)128 * 128 * 2);
    bf16_t* w2l  = (bf16_t*)(ws + off); off += align_up((size_t)128 * 128 * 2);

    // --- graph preprocessing ---
    hipMemsetAsync(deg, 0, (size_t)N * 4, stream);
    count_deg<<<(E + 255) / 256, 256, 0, stream>>>(dst, E, deg);
    scan_block_sums<<<NB, 256, 0, stream>>>(deg, bsum, N);
    scan_offsets<<<NB, 256, 0, stream>>>(deg, bsum, offs, curs, N, NB);
    compute_dinv<<<(N + 255) / 256, 256, 0, stream>>>(deg, dinv, N);
    scatter_csr<<<(E + 255) / 256, 256, 0, stream>>>(src, dst, E, dinv, curs, csrs, csrv);
    fill_self_pad<<<(N + 255) / 256, 256, 0, stream>>>(offs, deg, dinv, csrs, csrv, N);

    // --- weights -> transposed bf16 hi/lo ---
    convert_wt<<<(512 * 128 + 255) / 256, 256, 0, stream>>>(W1, w1h, w1l, 512);
    convert_wt<<<(128 * 128 + 255) / 256, 256, 0, stream>>>(W2, w2h, w2l, 128);

    // --- MLP: hA = BN1(relu(x@W1+b1)); h0 = BN2(hA@W2+b2) ---
    gemm_mfma_bn<<<(N + 63) / 64, 128, 0, stream>>>(
        x, w1h, w1l, b1, g1, be1, m1, v1, hA, N, 512, 1);
    gemm_mfma_bn<<<(N + 63) / 64, 128, 0, stream>>>(
        hA, w2h, w2l, b2, g2, be2, m2, v2, h0, N, 128, 0);

    // --- 10 propagation steps; step 10 lands in d_out ---
    const float* cur = h0;
    for (int k = 0; k < 10; ++k) {
        float* nxt = (k & 1) ? (float*)d_out : hA;
        appnp_step<<<(N + 3) / 4, 256, 0, stream>>>(
            cur, h0, offs, csrs, csrv, nxt, N);
        cur = nxt;
    }

    (void)n_in; (void)out_size; (void)ws_size;
}

// Round 6
// 795.959 us; speedup vs baseline: 1.0059x; 1.0059x over previous
//
#include <hip/hip_runtime.h>

#define ALPHA_F 0.1f
#define EPS_F   1e-5f

typedef __bf16 bf16_t;
typedef __bf16 bf16x8 __attribute__((ext_vector_type(8)));
typedef float  f32x4  __attribute__((ext_vector_type(4)));
typedef unsigned short u16x8 __attribute__((ext_vector_type(8)));

// padded count per node: self-loop + edges, rounded up to multiple of 8
__device__ __forceinline__ int pad_cnt(int d) { return (d + 8) & ~7; }

// ---------------------------------------------------------------------------
// W [K x 128] fp32  ->  Wt_hi/Wt_lo [128 x K] bf16 (transposed, hi/lo split)
// ---------------------------------------------------------------------------
__global__ void convert_wt(const float* __restrict__ W,
                           bf16_t* __restrict__ hi, bf16_t* __restrict__ lo, int K)
{
    int idx = blockIdx.x * 256 + threadIdx.x;
    if (idx < K * 128) {
        int k = idx >> 7, n = idx & 127;
        float f  = W[idx];
        bf16_t h = (bf16_t)f;
        hi[(size_t)n * K + k] = h;
        lo[(size_t)n * K + k] = (bf16_t)(f - (float)h);
    }
}

// ---------------------------------------------------------------------------
// out[M,128] = BN( act(A[M,K] @ W[K,128] + bias) ), MFMA bf16x3 (near-fp32).
// ---------------------------------------------------------------------------
__global__ __launch_bounds__(128) void gemm_mfma_bn(
    const float* __restrict__ A,
    const bf16_t* __restrict__ Wthi, const bf16_t* __restrict__ Wtlo,  // [128][K]
    const float* __restrict__ bias,
    const float* __restrict__ gamma, const float* __restrict__ beta,
    const float* __restrict__ mean,  const float* __restrict__ var,
    float* __restrict__ out, int M, int K, int do_relu)
{
    __shared__ __align__(16) unsigned short WH[128][40];
    __shared__ __align__(16) unsigned short WL[128][40];

    const int t   = threadIdx.x;       // 0..127
    const int w   = t >> 6;            // wave 0..1
    const int l   = t & 63;
    const int l15 = l & 15;
    const int lk  = l >> 4;            // k-group 0..3
    const int bm  = blockIdx.x * 64;

    f32x4 acc[2][8];
#pragma unroll
    for (int m = 0; m < 2; ++m)
#pragma unroll
        for (int f = 0; f < 8; ++f) acc[m][f] = (f32x4){0.f, 0.f, 0.f, 0.f};

    for (int k0 = 0; k0 < K; k0 += 32) {
        f32x4 x0[2], x1[2];
#pragma unroll
        for (int m = 0; m < 2; ++m) {
            int r = bm + w * 32 + m * 16 + l15;
            x0[m] = (f32x4){0.f, 0.f, 0.f, 0.f};
            x1[m] = x0[m];
            if (r < M) {
                const float* ap = A + (size_t)r * K + k0 + lk * 8;
                x0[m] = *(const f32x4*)ap;
                x1[m] = *(const f32x4*)(ap + 4);
            }
        }
        {
            const bf16_t* gh = Wthi + (size_t)t * K + k0;
            const bf16_t* gl = Wtlo + (size_t)t * K + k0;
#pragma unroll
            for (int c = 0; c < 4; ++c) {
                *(u16x8*)&WH[t][c * 8] = *(const u16x8*)(gh + c * 8);
                *(u16x8*)&WL[t][c * 8] = *(const u16x8*)(gl + c * 8);
            }
        }
        __syncthreads();

        bf16x8 ahi[2], alo[2];
#pragma unroll
        for (int m = 0; m < 2; ++m) {
#pragma unroll
            for (int j = 0; j < 4; ++j) {
                float f0 = x0[m][j];
                bf16_t h0 = (bf16_t)f0;
                ahi[m][j] = h0;
                alo[m][j] = (bf16_t)(f0 - (float)h0);
                float f1 = x1[m][j];
                bf16_t h1 = (bf16_t)f1;
                ahi[m][4 + j] = h1;
                alo[m][4 + j] = (bf16_t)(f1 - (float)h1);
            }
        }
#pragma unroll
        for (int f = 0; f < 8; ++f) {
            u16x8 uh = *(const u16x8*)&WH[f * 16 + l15][lk * 8];
            u16x8 ul = *(const u16x8*)&WL[f * 16 + l15][lk * 8];
            bf16x8 wh = __builtin_bit_cast(bf16x8, uh);
            bf16x8 wl = __builtin_bit_cast(bf16x8, ul);
#pragma unroll
            for (int m = 0; m < 2; ++m) {
                acc[m][f] = __builtin_amdgcn_mfma_f32_16x16x32_bf16(ahi[m], wh, acc[m][f], 0, 0, 0);
                acc[m][f] = __builtin_amdgcn_mfma_f32_16x16x32_bf16(alo[m], wh, acc[m][f], 0, 0, 0);
                acc[m][f] = __builtin_amdgcn_mfma_f32_16x16x32_bf16(ahi[m], wl, acc[m][f], 0, 0, 0);
            }
        }
        __syncthreads();
    }

#pragma unroll
    for (int f = 0; f < 8; ++f) {
        int col  = f * 16 + l15;
        float s  = gamma[col] * rsqrtf(var[col] + EPS_F);
        float sh = beta[col] - mean[col] * s;
        float bb = bias[col];
#pragma unroll
        for (int m = 0; m < 2; ++m) {
            int rbase = bm + w * 32 + m * 16 + lk * 4;
#pragma unroll
            for (int rr = 0; rr < 4; ++rr) {
                int rg = rbase + rr;
                if (rg < M) {
                    float v = acc[m][f][rr] + bb;
                    if (do_relu) v = fmaxf(v, 0.f);
                    out[(size_t)rg * 128 + col] = v * s + sh;
                }
            }
        }
    }
}

// ---------------------------------------------------------------------------
// Graph preprocessing (per launch)
// ---------------------------------------------------------------------------
__global__ void count_deg(const int* __restrict__ dst, int E, int* __restrict__ deg)
{
    int e = blockIdx.x * 256 + threadIdx.x;
    if (e < E) atomicAdd(&deg[dst[e]], 1);
}

// k1: per-block (1024 nodes) sum of padded counts
__global__ __launch_bounds__(256) void scan_block_sums(
    const int* __restrict__ deg, int* __restrict__ bsum, int N)
{
    __shared__ int sh[256];
    const int t  = threadIdx.x;
    const int i0 = blockIdx.x * 1024 + t * 4;
    int s = 0;
    if (i0 + 3 < N) {
        int4 d4 = *(const int4*)(deg + i0);
        s = pad_cnt(d4.x) + pad_cnt(d4.y) + pad_cnt(d4.z) + pad_cnt(d4.w);
    } else {
#pragma unroll
        for (int j = 0; j < 4; ++j)
            if (i0 + j < N) s += pad_cnt(deg[i0 + j]);
    }
    sh[t] = s;
    __syncthreads();
#pragma unroll
    for (int d = 128; d > 0; d >>= 1) {
        if (t < d) sh[t] += sh[t + d];
        __syncthreads();
    }
    if (t == 0) bsum[blockIdx.x] = sh[0];
}

// k2: per-block base (reduce of prior bsum) + local Hillis-Steele -> offs/cursor
__global__ __launch_bounds__(256) void scan_offsets(
    const int* __restrict__ deg, const int* __restrict__ bsum,
    int* __restrict__ offs, int* __restrict__ cursor, int N, int B)
{
    __shared__ int sh[256];
    __shared__ int sbase;
    const int b = blockIdx.x, t = threadIdx.x;

    int v = (t < b && t < B) ? bsum[t] : 0;   // B <= 256
    sh[t] = v;
    __syncthreads();
#pragma unroll
    for (int d = 128; d > 0; d >>= 1) {
        if (t < d) sh[t] += sh[t + d];
        __syncthreads();
    }
    if (t == 0) sbase = sh[0];
    __syncthreads();

    const int i0 = b * 1024 + t * 4;
    int c[4], s = 0;
#pragma unroll
    for (int j = 0; j < 4; ++j) {
        int i = i0 + j;
        c[j] = (i < N) ? pad_cnt(deg[i]) : 0;
        s += c[j];
    }
    sh[t] = s;
    __syncthreads();
    for (int d = 1; d < 256; d <<= 1) {
        int o = (t >= d) ? sh[t - d] : 0;
        __syncthreads();
        sh[t] += o;
        __syncthreads();
    }
    int run = sbase + sh[t] - s;   // exclusive prefix
#pragma unroll
    for (int j = 0; j < 4; ++j) {
        int i = i0 + j;
        if (i < N) {
            offs[i]   = run;
            cursor[i] = run;
            run += c[j];
        }
    }
    if (b == B - 1 && t == 255) offs[N] = run;
}

__global__ void compute_dinv(const int* __restrict__ deg, float* __restrict__ dinv, int N)
{
    int i = blockIdx.x * 256 + threadIdx.x;
    if (i < N) dinv[i] = rsqrtf((float)(deg[i] + 1));  // +1 self loop
}

__global__ void scatter_csr(const int* __restrict__ src, const int* __restrict__ dst,
                            int E, const float* __restrict__ dinv,
                            int* __restrict__ cursor,
                            int* __restrict__ csr_src, float* __restrict__ csr_val)
{
    int e = blockIdx.x * 256 + threadIdx.x;
    if (e < E) {
        int s = src[e], d = dst[e];
        int pos = atomicAdd(&cursor[d], 1);
        csr_src[pos] = s;
        csr_val[pos] = dinv[s] * dinv[d];
    }
}

__global__ void fill_self_pad(const int* __restrict__ offs, const int* __restrict__ deg,
                              const float* __restrict__ dinv,
                              int* __restrict__ csr_src, float* __restrict__ csr_val, int N)
{
    int i = blockIdx.x * 256 + threadIdx.x;
    if (i < N) {
        int base = offs[i], d = deg[i], end = offs[i + 1];
        float di = dinv[i];
        csr_src[base + d] = i;
        csr_val[base + d] = di * di;
        for (int p = base + d + 1; p < end; ++p) {
            csr_src[p] = i;
            csr_val[p] = 0.f;
        }
    }
}

// ---------------------------------------------------------------------------
// One APPNP step: nxt = (1-a)*(A_hat @ cur) + a*h0.  One wave per node,
// 64 lanes x float2 = 128 feats. Segments padded to x8 -> tail-free unroll-8,
// 8 gathers in flight per wave. CSR metadata via scalar loads (uniform addr).
// ---------------------------------------------------------------------------
__global__ __launch_bounds__(256) void appnp_step(
    const float* __restrict__ cur, const float* __restrict__ h0,
    const int* __restrict__ offs,
    const int* __restrict__ csr_src, const float* __restrict__ csr_val,
    float* __restrict__ nxt, int N)
{
    int wv = (int)((blockIdx.x * 256u + threadIdx.x) >> 6);
    if (wv >= N) return;
    const int i    = __builtin_amdgcn_readfirstlane(wv);
    const int lane = (int)(threadIdx.x & 63u);
    const int c    = lane * 2;

    int e   = offs[i];
    int end = offs[i + 1];
    float ax = 0.f, ay = 0.f;
    for (; e < end; e += 8) {
        int4   sa = *(const int4*)(csr_src + e);
        int4   sb = *(const int4*)(csr_src + e + 4);
        float4 wa = *(const float4*)(csr_val + e);
        float4 wb = *(const float4*)(csr_val + e + 4);
        float2 v0 = *(const float2*)(cur + (size_t)sa.x * 128 + c);
        float2 v1 = *(const float2*)(cur + (size_t)sa.y * 128 + c);
        float2 v2 = *(const float2*)(cur + (size_t)sa.z * 128 + c);
        float2 v3 = *(const float2*)(cur + (size_t)sa.w * 128 + c);
        float2 v4 = *(const float2*)(cur + (size_t)sb.x * 128 + c);
        float2 v5 = *(const float2*)(cur + (size_t)sb.y * 128 + c);
        float2 v6 = *(const float2*)(cur + (size_t)sb.z * 128 + c);
        float2 v7 = *(const float2*)(cur + (size_t)sb.w * 128 + c);
        ax = fmaf(wa.x, v0.x, ax); ay = fmaf(wa.x, v0.y, ay);
        ax = fmaf(wa.y, v1.x, ax); ay = fmaf(wa.y, v1.y, ay);
        ax = fmaf(wa.z, v2.x, ax); ay = fmaf(wa.z, v2.y, ay);
        ax = fmaf(wa.w, v3.x, ax); ay = fmaf(wa.w, v3.y, ay);
        ax = fmaf(wb.x, v4.x, ax); ay = fmaf(wb.x, v4.y, ay);
        ax = fmaf(wb.y, v5.x, ax); ay = fmaf(wb.y, v5.y, ay);
        ax = fmaf(wb.z, v6.x, ax); ay = fmaf(wb.z, v6.y, ay);
        ax = fmaf(wb.w, v7.x, ax); ay = fmaf(wb.w, v7.y, ay);
    }

    float2 h0v = *(const float2*)(h0 + (size_t)i * 128 + c);
    float2 o;
    o.x = ALPHA_F * h0v.x + (1.f - ALPHA_F) * ax;
    o.y = ALPHA_F * h0v.y + (1.f - ALPHA_F) * ay;
    *(float2*)(nxt + (size_t)i * 128 + c) = o;
}

// ---------------------------------------------------------------------------
static inline size_t align_up(size_t x) { return (x + 255) & ~(size_t)255; }

extern "C" void kernel_launch(void* const* d_in, const int* in_sizes, int n_in,
                              void* d_out, int out_size, void* d_ws, size_t ws_size,
                              hipStream_t stream)
{
    const float* x   = (const float*)d_in[0];
    const int*   ei  = (const int*)d_in[1];
    const float* W1  = (const float*)d_in[2];
    const float* b1  = (const float*)d_in[3];
    const float* g1  = (const float*)d_in[4];
    const float* be1 = (const float*)d_in[5];
    const float* m1  = (const float*)d_in[6];
    const float* v1  = (const float*)d_in[7];
    const float* W2  = (const float*)d_in[8];
    const float* b2  = (const float*)d_in[9];
    const float* g2  = (const float*)d_in[10];
    const float* be2 = (const float*)d_in[11];
    const float* m2  = (const float*)d_in[12];
    const float* v2  = (const float*)d_in[13];

    const int N = in_sizes[0] / 512;   // 50000
    const int E = in_sizes[1] / 2;     // 800000
    const int* src = ei;
    const int* dst = ei + E;
    const int CSR_CAP = E + 8 * N;
    const int NB = (N + 1023) / 1024;  // scan blocks (49)

    char* ws = (char*)d_ws;
    size_t off = 0;
    float*  h0   = (float*)(ws + off);  off += align_up((size_t)N * 128 * 4);
    float*  hA   = (float*)(ws + off);  off += align_up((size_t)N * 128 * 4);
    int*    deg  = (int*)(ws + off);    off += align_up((size_t)N * 4);
    float*  dinv = (float*)(ws + off);  off += align_up((size_t)N * 4);
    int*    offs = (int*)(ws + off);    off += align_up((size_t)(N + 1) * 4);
    int*    curs = (int*)(ws + off);    off += align_up((size_t)N * 4);
    int*    bsum = (int*)(ws + off);    off += align_up((size_t)256 * 4);
    int*    csrs = (int*)(ws + off);    off += align_up((size_t)CSR_CAP * 4);
    float*  csrv = (float*)(ws + off);  off += align_up((size_t)CSR_CAP * 4);
    bf16_t* w1h  = (bf16_t*)(ws + off); off += align_up((size_t)512 * 128 * 2);
    bf16_t* w1l  = (bf16_t*)(ws + off); off += align_up((size_t)512 * 128 * 2);
    bf16_t* w2h  = (bf16_t*)(ws + off); off += align_up((size_t)128 * 128 * 2);
    bf16_t* w2l  = (bf16_t*)(ws + off); off += align_up((size_t)128 * 128 * 2);

    // --- graph preprocessing ---
    hipMemsetAsync(deg, 0, (size_t)N * 4, stream);
    count_deg<<<(E + 255) / 256, 256, 0, stream>>>(dst, E, deg);
    scan_block_sums<<<NB, 256, 0, stream>>>(deg, bsum, N);
    scan_offsets<<<NB, 256, 0, stream>>>(deg, bsum, offs, curs, N, NB);
    compute_dinv<<<(N + 255) / 256, 256, 0, stream>>>(deg, dinv, N);
    scatter_csr<<<(E + 255) / 256, 256, 0, stream>>>(src, dst, E, dinv, curs, csrs, csrv);
    fill_self_pad<<<(N + 255) / 256, 256, 0, stream>>>(offs, deg, dinv, csrs, csrv, N);

    // --- weights -> transposed bf16 hi/lo ---
    convert_wt<<<(512 * 128 + 255) / 256, 256, 0, stream>>>(W1, w1h, w1l, 512);
    convert_wt<<<(128 * 128 + 255) / 256, 256, 0, stream>>>(W2, w2h, w2l, 128);

    // --- MLP: hA = BN1(relu(x@W1+b1)); h0 = BN2(hA@W2+b2) ---
    gemm_mfma_bn<<<(N + 63) / 64, 128, 0, stream>>>(
        x, w1h, w1l, b1, g1, be1, m1, v1, hA, N, 512, 1);
    gemm_mfma_bn<<<(N + 63) / 64, 128, 0, stream>>>(
        hA, w2h, w2l, b2, g2, be2, m2, v2, h0, N, 128, 0);

    // --- 10 propagation steps; step 10 lands in d_out ---
    const float* cur = h0;
    for (int k = 0; k < 10; ++k) {
        float* nxt = (k & 1) ? (float*)d_out : hA;
        appnp_step<<<(N + 3) / 4, 256, 0, stream>>>(
            cur, h0, offs, csrs, csrv, nxt, N);
        cur = nxt;
    }

    (void)n_in; (void)out_size; (void)ws_size;
}

// Round 7
// 521.894 us; speedup vs baseline: 1.5342x; 1.5251x over previous
//
#include <hip/hip_runtime.h>

#define ALPHA_F 0.1f
#define EPS_F   1e-5f

typedef __bf16 bf16_t;
typedef __bf16 bf16x8 __attribute__((ext_vector_type(8)));
typedef float  f32x4  __attribute__((ext_vector_type(4)));
typedef unsigned short u16x8 __attribute__((ext_vector_type(8)));
typedef _Float16 h16x4 __attribute__((ext_vector_type(4)));
typedef _Float16 h16x8 __attribute__((ext_vector_type(8)));

// padded count per node: self-loop + edges, rounded up to multiple of 8
__device__ __forceinline__ int pad_cnt(int d) { return (d + 8) & ~7; }

// ---------------------------------------------------------------------------
// W [K x 128] fp32  ->  Wt_hi/Wt_lo [128 x K] bf16 (transposed, hi/lo split)
// ---------------------------------------------------------------------------
__global__ void convert_wt(const float* __restrict__ W,
                           bf16_t* __restrict__ hi, bf16_t* __restrict__ lo, int K)
{
    int idx = blockIdx.x * 256 + threadIdx.x;
    if (idx < K * 128) {
        int k = idx >> 7, n = idx & 127;
        float f  = W[idx];
        bf16_t h = (bf16_t)f;
        hi[(size_t)n * K + k] = h;
        lo[(size_t)n * K + k] = (bf16_t)(f - (float)h);
    }
}

// ---------------------------------------------------------------------------
// out[M,128] = BN( act(A[M,K] @ W[K,128] + bias) ), MFMA bf16x3 (near-fp32).
// 256 thr = 4 waves, 16 rows/wave (3128 waves chip-wide -> ~38% occ cap).
// W tile (128n x 32k hi+lo) double-buffered in LDS, ONE barrier per k-step.
// A prefetched one k-step ahead in registers.
// ---------------------------------------------------------------------------
template<bool A_HALF, bool OUT_HALF>
__global__ __launch_bounds__(256) void gemm_mfma_bn(
    const void* __restrict__ Av,
    const bf16_t* __restrict__ Wthi, const bf16_t* __restrict__ Wtlo,  // [128][K]
    const float* __restrict__ bias,
    const float* __restrict__ gamma, const float* __restrict__ beta,
    const float* __restrict__ mean,  const float* __restrict__ var,
    void* __restrict__ outv, int M, int K, int do_relu)
{
    __shared__ __align__(16) unsigned short WH[2][128][40];
    __shared__ __align__(16) unsigned short WL[2][128][40];

    const int t   = threadIdx.x;       // 0..255
    const int w   = t >> 6;            // wave 0..3
    const int l   = t & 63;
    const int l15 = l & 15;
    const int lk  = l >> 4;            // 0..3
    const int bm  = blockIdx.x * 64;
    const int r   = bm + w * 16 + l15; // this lane's A row
    const int nk  = K >> 5;

    const float*    Af = (const float*)Av;
    const _Float16* Ah = (const _Float16*)Av;

    f32x4 acc[8];
#pragma unroll
    for (int f = 0; f < 8; ++f) acc[f] = (f32x4){0.f, 0.f, 0.f, 0.f};

    float a_cur[8], a_nxt[8];

    auto loadA = [&](int kbase, float* dst) {
        if (r < M) {
            if (A_HALF) {
                h16x8 v = *(const h16x8*)(Ah + (size_t)r * K + kbase + lk * 8);
#pragma unroll
                for (int j = 0; j < 8; ++j) dst[j] = (float)v[j];
            } else {
                f32x4 v0 = *(const f32x4*)(Af + (size_t)r * K + kbase + lk * 8);
                f32x4 v1 = *(const f32x4*)(Af + (size_t)r * K + kbase + lk * 8 + 4);
#pragma unroll
                for (int j = 0; j < 4; ++j) { dst[j] = v0[j]; dst[4 + j] = v1[j]; }
            }
        } else {
#pragma unroll
            for (int j = 0; j < 8; ++j) dst[j] = 0.f;
        }
    };

    auto stageW = [&](int buf, int kbase) {
        const bf16_t* g = ((t < 128) ? Wthi : Wtlo) + (size_t)(t & 127) * K + kbase;
        unsigned short* d = (t < 128) ? &WH[buf][t & 127][0] : &WL[buf][t & 127][0];
#pragma unroll
        for (int c = 0; c < 4; ++c)
            *(u16x8*)&d[c * 8] = *(const u16x8*)(g + c * 8);
    };

    loadA(0, a_cur);
    stageW(0, 0);
    __syncthreads();

    for (int i = 0; i < nk; ++i) {
        const int kn = (i + 1) << 5;
        if (kn < K) {
            loadA(kn, a_nxt);
            stageW((i + 1) & 1, kn);
        }
        // convert current A to hi/lo bf16
        bf16x8 ahi, alo;
#pragma unroll
        for (int j = 0; j < 8; ++j) {
            float  f0 = a_cur[j];
            bf16_t h0 = (bf16_t)f0;
            ahi[j] = h0;
            alo[j] = (bf16_t)(f0 - (float)h0);
        }
        const int buf = i & 1;
#pragma unroll
        for (int f = 0; f < 8; ++f) {
            u16x8 uh = *(const u16x8*)&WH[buf][f * 16 + l15][lk * 8];
            u16x8 ul = *(const u16x8*)&WL[buf][f * 16 + l15][lk * 8];
            bf16x8 wh = __builtin_bit_cast(bf16x8, uh);
            bf16x8 wl = __builtin_bit_cast(bf16x8, ul);
            acc[f] = __builtin_amdgcn_mfma_f32_16x16x32_bf16(ahi, wh, acc[f], 0, 0, 0);
            acc[f] = __builtin_amdgcn_mfma_f32_16x16x32_bf16(alo, wh, acc[f], 0, 0, 0);
            acc[f] = __builtin_amdgcn_mfma_f32_16x16x32_bf16(ahi, wl, acc[f], 0, 0, 0);
        }
        __syncthreads();
#pragma unroll
        for (int j = 0; j < 8; ++j) a_cur[j] = a_nxt[j];
    }

    // epilogue: bias -> (relu) -> BN.  D: col=l15, row=lk*4+rr
#pragma unroll
    for (int f = 0; f < 8; ++f) {
        int col  = f * 16 + l15;
        float s  = gamma[col] * rsqrtf(var[col] + EPS_F);
        float sh = beta[col] - mean[col] * s;
        float bb = bias[col];
#pragma unroll
        for (int rr = 0; rr < 4; ++rr) {
            int rg = bm + w * 16 + lk * 4 + rr;
            if (rg < M) {
                float v = acc[f][rr] + bb;
                if (do_relu) v = fmaxf(v, 0.f);
                v = v * s + sh;
                if (OUT_HALF) ((_Float16*)outv)[(size_t)rg * 128 + col] = (_Float16)v;
                else          ((float*)outv)[(size_t)rg * 128 + col]    = v;
            }
        }
    }
}

// ---------------------------------------------------------------------------
// Graph preprocessing (per launch)
// ---------------------------------------------------------------------------
__global__ void count_deg(const int* __restrict__ dst, int E, int* __restrict__ deg)
{
    int e = blockIdx.x * 256 + threadIdx.x;
    if (e < E) atomicAdd(&deg[dst[e]], 1);
}

__global__ __launch_bounds__(256) void scan_block_sums(
    const int* __restrict__ deg, int* __restrict__ bsum, int N)
{
    __shared__ int sh[256];
    const int t  = threadIdx.x;
    const int i0 = blockIdx.x * 1024 + t * 4;
    int s = 0;
    if (i0 + 3 < N) {
        int4 d4 = *(const int4*)(deg + i0);
        s = pad_cnt(d4.x) + pad_cnt(d4.y) + pad_cnt(d4.z) + pad_cnt(d4.w);
    } else {
#pragma unroll
        for (int j = 0; j < 4; ++j)
            if (i0 + j < N) s += pad_cnt(deg[i0 + j]);
    }
    sh[t] = s;
    __syncthreads();
#pragma unroll
    for (int d = 128; d > 0; d >>= 1) {
        if (t < d) sh[t] += sh[t + d];
        __syncthreads();
    }
    if (t == 0) bsum[blockIdx.x] = sh[0];
}

__global__ __launch_bounds__(256) void scan_offsets(
    const int* __restrict__ deg, const int* __restrict__ bsum,
    int* __restrict__ offs, int* __restrict__ cursor, int N, int B)
{
    __shared__ int sh[256];
    __shared__ int sbase;
    const int b = blockIdx.x, t = threadIdx.x;

    int v = (t < b && t < B) ? bsum[t] : 0;   // B <= 256
    sh[t] = v;
    __syncthreads();
#pragma unroll
    for (int d = 128; d > 0; d >>= 1) {
        if (t < d) sh[t] += sh[t + d];
        __syncthreads();
    }
    if (t == 0) sbase = sh[0];
    __syncthreads();

    const int i0 = b * 1024 + t * 4;
    int c[4], s = 0;
#pragma unroll
    for (int j = 0; j < 4; ++j) {
        int i = i0 + j;
        c[j] = (i < N) ? pad_cnt(deg[i]) : 0;
        s += c[j];
    }
    sh[t] = s;
    __syncthreads();
    for (int d = 1; d < 256; d <<= 1) {
        int o = (t >= d) ? sh[t - d] : 0;
        __syncthreads();
        sh[t] += o;
        __syncthreads();
    }
    int run = sbase + sh[t] - s;   // exclusive prefix
#pragma unroll
    for (int j = 0; j < 4; ++j) {
        int i = i0 + j;
        if (i < N) {
            offs[i]   = run;
            cursor[i] = run;
            run += c[j];
        }
    }
    if (b == B - 1 && t == 255) offs[N] = run;
}

__global__ void compute_dinv(const int* __restrict__ deg, float* __restrict__ dinv, int N)
{
    int i = blockIdx.x * 256 + threadIdx.x;
    if (i < N) dinv[i] = rsqrtf((float)(deg[i] + 1));  // +1 self loop
}

__global__ void scatter_csr(const int* __restrict__ src, const int* __restrict__ dst,
                            int E, const float* __restrict__ dinv,
                            int* __restrict__ cursor,
                            int* __restrict__ csr_src, float* __restrict__ csr_val)
{
    int e = blockIdx.x * 256 + threadIdx.x;
    if (e < E) {
        int s = src[e], d = dst[e];
        int pos = atomicAdd(&cursor[d], 1);
        csr_src[pos] = s;
        csr_val[pos] = dinv[s] * dinv[d];
    }
}

__global__ void fill_self_pad(const int* __restrict__ offs, const int* __restrict__ deg,
                              const float* __restrict__ dinv,
                              int* __restrict__ csr_src, float* __restrict__ csr_val, int N)
{
    int i = blockIdx.x * 256 + threadIdx.x;
    if (i < N) {
        int base = offs[i], d = deg[i], end = offs[i + 1];
        float di = dinv[i];
        csr_src[base + d] = i;
        csr_val[base + d] = di * di;
        for (int p = base + d + 1; p < end; ++p) {
            csr_src[p] = i;
            csr_val[p] = 0.f;
        }
    }
}

// ---------------------------------------------------------------------------
// One APPNP step (fp16 features): nxt = (1-a)*(A_hat @ cur) + a*h0.
// One wave per node; 2 half-waves process 2 edge-groups concurrently:
// lanes 0-31 edges [e,e+4), lanes 32-63 edges [e+4,e+8); each lane 4 feats
// (8 B). Cross-half __shfl_xor(32) reduce at the end. fp32 accumulation.
// Final step writes fp32 to fout instead of fp16 nxt.
// ---------------------------------------------------------------------------
__global__ __launch_bounds__(256) void appnp_step(
    const _Float16* __restrict__ cur, const _Float16* __restrict__ h0,
    const int* __restrict__ offs,
    const int* __restrict__ csr_src, const float* __restrict__ csr_val,
    _Float16* __restrict__ nxt, float* __restrict__ fout, int N)
{
    int wv = (int)((blockIdx.x * 256u + threadIdx.x) >> 6);
    if (wv >= N) return;
    const int i    = __builtin_amdgcn_readfirstlane(wv);
    const int lane = (int)(threadIdx.x & 63u);
    const int half = lane >> 5;
    const int fl   = (lane & 31) * 4;

    int e   = offs[i];
    int end = offs[i + 1];
    f32x4 acc = (f32x4){0.f, 0.f, 0.f, 0.f};
    for (; e < end; e += 8) {
        const int base = e + half * 4;
        int4  s4 = *(const int4*)(csr_src + base);
        f32x4 w4 = *(const f32x4*)(csr_val + base);
        h16x4 v0 = *(const h16x4*)(cur + (size_t)s4.x * 128 + fl);
        h16x4 v1 = *(const h16x4*)(cur + (size_t)s4.y * 128 + fl);
        h16x4 v2 = *(const h16x4*)(cur + (size_t)s4.z * 128 + fl);
        h16x4 v3 = *(const h16x4*)(cur + (size_t)s4.w * 128 + fl);
#pragma unroll
        for (int j = 0; j < 4; ++j) {
            acc[j] = fmaf(w4[0], (float)v0[j], acc[j]);
            acc[j] = fmaf(w4[1], (float)v1[j], acc[j]);
            acc[j] = fmaf(w4[2], (float)v2[j], acc[j]);
            acc[j] = fmaf(w4[3], (float)v3[j], acc[j]);
        }
    }

    // combine the two half-wave partial sums
#pragma unroll
    for (int j = 0; j < 4; ++j) acc[j] += __shfl_xor(acc[j], 32);

    if (half == 0) {
        h16x4 hv = *(const h16x4*)(h0 + (size_t)i * 128 + fl);
        f32x4 o;
#pragma unroll
        for (int j = 0; j < 4; ++j)
            o[j] = ALPHA_F * (float)hv[j] + (1.f - ALPHA_F) * acc[j];
        if (fout) {
            *(f32x4*)(fout + (size_t)i * 128 + fl) = o;
        } else {
            h16x4 o16;
#pragma unroll
            for (int j = 0; j < 4; ++j) o16[j] = (_Float16)o[j];
            *(h16x4*)(nxt + (size_t)i * 128 + fl) = o16;
        }
    }
}

// ---------------------------------------------------------------------------
static inline size_t align_up(size_t x) { return (x + 255) & ~(size_t)255; }

extern "C" void kernel_launch(void* const* d_in, const int* in_sizes, int n_in,
                              void* d_out, int out_size, void* d_ws, size_t ws_size,
                              hipStream_t stream)
{
    const float* x   = (const float*)d_in[0];
    const int*   ei  = (const int*)d_in[1];
    const float* W1  = (const float*)d_in[2];
    const float* b1  = (const float*)d_in[3];
    const float* g1  = (const float*)d_in[4];
    const float* be1 = (const float*)d_in[5];
    const float* m1  = (const float*)d_in[6];
    const float* v1  = (const float*)d_in[7];
    const float* W2  = (const float*)d_in[8];
    const float* b2  = (const float*)d_in[9];
    const float* g2  = (const float*)d_in[10];
    const float* be2 = (const float*)d_in[11];
    const float* m2  = (const float*)d_in[12];
    const float* v2  = (const float*)d_in[13];

    const int N = in_sizes[0] / 512;   // 50000
    const int E = in_sizes[1] / 2;     // 800000
    const int* src = ei;
    const int* dst = ei + E;
    const int CSR_CAP = E + 8 * N;
    const int NB = (N + 1023) / 1024;  // 49

    char* ws = (char*)d_ws;
    size_t off = 0;
    _Float16* hAh = (_Float16*)(ws + off); off += align_up((size_t)N * 128 * 2);
    _Float16* h0h = (_Float16*)(ws + off); off += align_up((size_t)N * 128 * 2);
    _Float16* p0  = (_Float16*)(ws + off); off += align_up((size_t)N * 128 * 2);
    _Float16* p1  = (_Float16*)(ws + off); off += align_up((size_t)N * 128 * 2);
    int*    deg  = (int*)(ws + off);    off += align_up((size_t)N * 4);
    float*  dinv = (float*)(ws + off);  off += align_up((size_t)N * 4);
    int*    offs = (int*)(ws + off);    off += align_up((size_t)(N + 1) * 4);
    int*    curs = (int*)(ws + off);    off += align_up((size_t)N * 4);
    int*    bsum = (int*)(ws + off);    off += align_up((size_t)256 * 4);
    int*    csrs = (int*)(ws + off);    off += align_up((size_t)CSR_CAP * 4);
    float*  csrv = (float*)(ws + off);  off += align_up((size_t)CSR_CAP * 4);
    bf16_t* w1h  = (bf16_t*)(ws + off); off += align_up((size_t)512 * 128 * 2);
    bf16_t* w1l  = (bf16_t*)(ws + off); off += align_up((size_t)512 * 128 * 2);
    bf16_t* w2h  = (bf16_t*)(ws + off); off += align_up((size_t)128 * 128 * 2);
    bf16_t* w2l  = (bf16_t*)(ws + off); off += align_up((size_t)128 * 128 * 2);

    // --- graph preprocessing ---
    hipMemsetAsync(deg, 0, (size_t)N * 4, stream);
    count_deg<<<(E + 255) / 256, 256, 0, stream>>>(dst, E, deg);
    scan_block_sums<<<NB, 256, 0, stream>>>(deg, bsum, N);
    scan_offsets<<<NB, 256, 0, stream>>>(deg, bsum, offs, curs, N, NB);
    compute_dinv<<<(N + 255) / 256, 256, 0, stream>>>(deg, dinv, N);
    scatter_csr<<<(E + 255) / 256, 256, 0, stream>>>(src, dst, E, dinv, curs, csrs, csrv);
    fill_self_pad<<<(N + 255) / 256, 256, 0, stream>>>(offs, deg, dinv, csrs, csrv, N);

    // --- weights -> transposed bf16 hi/lo ---
    convert_wt<<<(512 * 128 + 255) / 256, 256, 0, stream>>>(W1, w1h, w1l, 512);
    convert_wt<<<(128 * 128 + 255) / 256, 256, 0, stream>>>(W2, w2h, w2l, 128);

    // --- MLP: hAh = BN1(relu(x@W1+b1)) fp16; h0h = BN2(hAh@W2+b2) fp16 ---
    gemm_mfma_bn<false, true><<<(N + 63) / 64, 256, 0, stream>>>(
        x, w1h, w1l, b1, g1, be1, m1, v1, hAh, N, 512, 1);
    gemm_mfma_bn<true, true><<<(N + 63) / 64, 256, 0, stream>>>(
        hAh, w2h, w2l, b2, g2, be2, m2, v2, h0h, N, 128, 0);

    // --- 10 propagation steps (fp16 ping-pong); step 10 writes fp32 d_out ---
    const _Float16* cur = h0h;
    for (int k = 0; k < 10; ++k) {
        _Float16* nxt = (k & 1) ? p1 : p0;
        float* fo = (k == 9) ? (float*)d_out : nullptr;
        appnp_step<<<(N + 3) / 4, 256, 0, stream>>>(
            cur, h0h, offs, csrs, csrv, nxt, fo, N);
        cur = nxt;
    }

    (void)n_in; (void)out_size; (void)ws_size;
}

// Round 8
// 494.072 us; speedup vs baseline: 1.6206x; 1.0563x over previous
//
#include <hip/hip_runtime.h>

#define ALPHA_F 0.1f
#define EPS_F   1e-5f

typedef __bf16 bf16_t;
typedef __bf16 bf16x8 __attribute__((ext_vector_type(8)));
typedef float  f32x4  __attribute__((ext_vector_type(4)));
typedef unsigned short u16x8 __attribute__((ext_vector_type(8)));
typedef _Float16 h16x4 __attribute__((ext_vector_type(4)));
typedef _Float16 h16x8 __attribute__((ext_vector_type(8)));

// padded count per node: self-loop + edges, rounded up to multiple of 8
__device__ __forceinline__ int pad_cnt(int d) { return (d + 8) & ~7; }

// ---------------------------------------------------------------------------
// W [K x 128] fp32  ->  Wt_hi/Wt_lo [128 x K] bf16 (transposed, hi/lo split)
// ---------------------------------------------------------------------------
__global__ void convert_wt(const float* __restrict__ W,
                           bf16_t* __restrict__ hi, bf16_t* __restrict__ lo, int K)
{
    int idx = blockIdx.x * 256 + threadIdx.x;
    if (idx < K * 128) {
        int k = idx >> 7, n = idx & 127;
        float f  = W[idx];
        bf16_t h = (bf16_t)f;
        hi[(size_t)n * K + k] = h;
        lo[(size_t)n * K + k] = (bf16_t)(f - (float)h);
    }
}

// ---------------------------------------------------------------------------
// out[M,128] = BN( act(A[M,K] @ W[K,128] + bias) ), MFMA bf16x3 (near-fp32).
// T14 issue-early/write-late: next k-step's W is global-loaded into REGS
// during this step's MFMAs and ds_written at the top of the next step.
// Single-buffer LDS, 2 barriers/step, no global latency on the barrier path.
// ---------------------------------------------------------------------------
template<bool A_HALF, bool OUT_HALF>
__global__ __launch_bounds__(256) void gemm_mfma_bn(
    const void* __restrict__ Av,
    const bf16_t* __restrict__ Wthi, const bf16_t* __restrict__ Wtlo,  // [128][K]
    const float* __restrict__ bias,
    const float* __restrict__ gamma, const float* __restrict__ beta,
    const float* __restrict__ mean,  const float* __restrict__ var,
    void* __restrict__ outv, int M, int K, int do_relu)
{
    __shared__ __align__(16) unsigned short WH[128][40];
    __shared__ __align__(16) unsigned short WL[128][40];

    const int t   = threadIdx.x;       // 0..255
    const int w   = t >> 6;            // wave 0..3
    const int l   = t & 63;
    const int l15 = l & 15;
    const int lk  = l >> 4;            // 0..3
    const int bm  = blockIdx.x * 64;
    const int r   = bm + w * 16 + l15; // this lane's A row
    const int nk  = K >> 5;

    const float*    Af = (const float*)Av;
    const _Float16* Ah = (const _Float16*)Av;

    // W staging ownership: threads 0-127 own WH rows, 128-255 own WL rows.
    const bf16_t* Wsrc = ((t < 128) ? Wthi : Wtlo) + (size_t)(t & 127) * K;
    unsigned short* Wdst = (t < 128) ? &WH[t & 127][0] : &WL[t & 127][0];

    f32x4 acc[8];
#pragma unroll
    for (int f = 0; f < 8; ++f) acc[f] = (f32x4){0.f, 0.f, 0.f, 0.f};

    float a_cur[8], a_nxt[8];
    u16x8 wreg[4], wreg_n[4];

    auto loadA = [&](int kbase, float* dstv) {
        if (r < M) {
            if (A_HALF) {
                h16x8 v = *(const h16x8*)(Ah + (size_t)r * K + kbase + lk * 8);
#pragma unroll
                for (int j = 0; j < 8; ++j) dstv[j] = (float)v[j];
            } else {
                f32x4 v0 = *(const f32x4*)(Af + (size_t)r * K + kbase + lk * 8);
                f32x4 v1 = *(const f32x4*)(Af + (size_t)r * K + kbase + lk * 8 + 4);
#pragma unroll
                for (int j = 0; j < 4; ++j) { dstv[j] = v0[j]; dstv[4 + j] = v1[j]; }
            }
        } else {
#pragma unroll
            for (int j = 0; j < 8; ++j) dstv[j] = 0.f;
        }
    };

    // prologue: k-step 0 into regs
#pragma unroll
    for (int c = 0; c < 4; ++c) wreg[c] = *(const u16x8*)(Wsrc + c * 8);
    loadA(0, a_cur);

    for (int i = 0; i < nk; ++i) {
        // write-late: current W (loaded last iter) into LDS
#pragma unroll
        for (int c = 0; c < 4; ++c) *(u16x8*)&Wdst[c * 8] = wreg[c];

        // issue-early: next k-step's global loads (regs, consumed next iter)
        const int kn = (i + 1) << 5;
        if (kn < K) {
#pragma unroll
            for (int c = 0; c < 4; ++c) wreg_n[c] = *(const u16x8*)(Wsrc + kn + c * 8);
            loadA(kn, a_nxt);
        }
        __syncthreads();

        // convert current A to hi/lo bf16
        bf16x8 ahi, alo;
#pragma unroll
        for (int j = 0; j < 8; ++j) {
            float  f0 = a_cur[j];
            bf16_t h0 = (bf16_t)f0;
            ahi[j] = h0;
            alo[j] = (bf16_t)(f0 - (float)h0);
        }
#pragma unroll
        for (int f = 0; f < 8; ++f) {
            u16x8 uh = *(const u16x8*)&WH[f * 16 + l15][lk * 8];
            u16x8 ul = *(const u16x8*)&WL[f * 16 + l15][lk * 8];
            bf16x8 wh = __builtin_bit_cast(bf16x8, uh);
            bf16x8 wl = __builtin_bit_cast(bf16x8, ul);
            acc[f] = __builtin_amdgcn_mfma_f32_16x16x32_bf16(ahi, wh, acc[f], 0, 0, 0);
            acc[f] = __builtin_amdgcn_mfma_f32_16x16x32_bf16(alo, wh, acc[f], 0, 0, 0);
            acc[f] = __builtin_amdgcn_mfma_f32_16x16x32_bf16(ahi, wl, acc[f], 0, 0, 0);
        }
        __syncthreads();   // reads done before next iter's ds_write
#pragma unroll
        for (int j = 0; j < 8; ++j) a_cur[j] = a_nxt[j];
#pragma unroll
        for (int c = 0; c < 4; ++c) wreg[c] = wreg_n[c];
    }

    // epilogue: bias -> (relu) -> BN.  D: col=l15, row=lk*4+rr
#pragma unroll
    for (int f = 0; f < 8; ++f) {
        int col  = f * 16 + l15;
        float s  = gamma[col] * rsqrtf(var[col] + EPS_F);
        float sh = beta[col] - mean[col] * s;
        float bb = bias[col];
#pragma unroll
        for (int rr = 0; rr < 4; ++rr) {
            int rg = bm + w * 16 + lk * 4 + rr;
            if (rg < M) {
                float v = acc[f][rr] + bb;
                if (do_relu) v = fmaxf(v, 0.f);
                v = v * s + sh;
                if (OUT_HALF) ((_Float16*)outv)[(size_t)rg * 128 + col] = (_Float16)v;
                else          ((float*)outv)[(size_t)rg * 128 + col]    = v;
            }
        }
    }
}

// ---------------------------------------------------------------------------
// Graph preprocessing (per launch)
// ---------------------------------------------------------------------------
__global__ void count_deg(const int* __restrict__ dst, int E, int* __restrict__ deg)
{
    int e = blockIdx.x * 256 + threadIdx.x;
    if (e < E) atomicAdd(&deg[dst[e]], 1);
}

__global__ __launch_bounds__(256) void scan_block_sums(
    const int* __restrict__ deg, int* __restrict__ bsum, int N)
{
    __shared__ int sh[256];
    const int t  = threadIdx.x;
    const int i0 = blockIdx.x * 1024 + t * 4;
    int s = 0;
    if (i0 + 3 < N) {
        int4 d4 = *(const int4*)(deg + i0);
        s = pad_cnt(d4.x) + pad_cnt(d4.y) + pad_cnt(d4.z) + pad_cnt(d4.w);
    } else {
#pragma unroll
        for (int j = 0; j < 4; ++j)
            if (i0 + j < N) s += pad_cnt(deg[i0 + j]);
    }
    sh[t] = s;
    __syncthreads();
#pragma unroll
    for (int d = 128; d > 0; d >>= 1) {
        if (t < d) sh[t] += sh[t + d];
        __syncthreads();
    }
    if (t == 0) bsum[blockIdx.x] = sh[0];
}

__global__ __launch_bounds__(256) void scan_offsets(
    const int* __restrict__ deg, const int* __restrict__ bsum,
    int* __restrict__ offs, int* __restrict__ cursor, int N, int B)
{
    __shared__ int sh[256];
    __shared__ int sbase;
    const int b = blockIdx.x, t = threadIdx.x;

    int v = (t < b && t < B) ? bsum[t] : 0;   // B <= 256
    sh[t] = v;
    __syncthreads();
#pragma unroll
    for (int d = 128; d > 0; d >>= 1) {
        if (t < d) sh[t] += sh[t + d];
        __syncthreads();
    }
    if (t == 0) sbase = sh[0];
    __syncthreads();

    const int i0 = b * 1024 + t * 4;
    int c[4], s = 0;
#pragma unroll
    for (int j = 0; j < 4; ++j) {
        int i = i0 + j;
        c[j] = (i < N) ? pad_cnt(deg[i]) : 0;
        s += c[j];
    }
    sh[t] = s;
    __syncthreads();
    for (int d = 1; d < 256; d <<= 1) {
        int o = (t >= d) ? sh[t - d] : 0;
        __syncthreads();
        sh[t] += o;
        __syncthreads();
    }
    int run = sbase + sh[t] - s;   // exclusive prefix
#pragma unroll
    for (int j = 0; j < 4; ++j) {
        int i = i0 + j;
        if (i < N) {
            offs[i]   = run;
            cursor[i] = run;
            run += c[j];
        }
    }
    if (b == B - 1 && t == 255) offs[N] = run;
}

__global__ void compute_dinv(const int* __restrict__ deg, float* __restrict__ dinv, int N)
{
    int i = blockIdx.x * 256 + threadIdx.x;
    if (i < N) dinv[i] = rsqrtf((float)(deg[i] + 1));  // +1 self loop
}

__global__ void scatter_csr(const int* __restrict__ src, const int* __restrict__ dst,
                            int E, const float* __restrict__ dinv,
                            int* __restrict__ cursor,
                            int* __restrict__ csr_src, float* __restrict__ csr_val)
{
    int e = blockIdx.x * 256 + threadIdx.x;
    if (e < E) {
        int s = src[e], d = dst[e];
        int pos = atomicAdd(&cursor[d], 1);
        csr_src[pos] = s;
        csr_val[pos] = dinv[s] * dinv[d];
    }
}

__global__ void fill_self_pad(const int* __restrict__ offs, const int* __restrict__ deg,
                              const float* __restrict__ dinv,
                              int* __restrict__ csr_src, float* __restrict__ csr_val, int N)
{
    int i = blockIdx.x * 256 + threadIdx.x;
    if (i < N) {
        int base = offs[i], d = deg[i], end = offs[i + 1];
        float di = dinv[i];
        csr_src[base + d] = i;
        csr_val[base + d] = di * di;
        for (int p = base + d + 1; p < end; ++p) {
            csr_src[p] = i;
            csr_val[p] = 0.f;
        }
    }
}

// ---------------------------------------------------------------------------
// One APPNP step (fp16 features): nxt = (1-a)*(A_hat @ cur) + a*h0.
// One wave per node; FOUR 16-lane groups, each lane 8 feats (16 B h16x8):
// one load instruction covers 4 edges; unroll-8 + 2-stage software pipeline
// keeps ~16 edge-row gathers in flight per wave. fp32 accumulation,
// butterfly __shfl_xor(16/32) combine. Final step writes fp32 to fout.
// ---------------------------------------------------------------------------
__global__ __launch_bounds__(256) void appnp_step(
    const _Float16* __restrict__ cur, const _Float16* __restrict__ h0,
    const int* __restrict__ offs,
    const int* __restrict__ csr_src, const float* __restrict__ csr_val,
    _Float16* __restrict__ nxt, float* __restrict__ fout, int N)
{
    int wv = (int)((blockIdx.x * 256u + threadIdx.x) >> 6);
    if (wv >= N) return;
    const int i    = __builtin_amdgcn_readfirstlane(wv);
    const int lane = (int)(threadIdx.x & 63u);
    const int g    = lane >> 4;          // group 0..3
    const int fl   = (lane & 15) * 8;    // feature offset

    int e   = offs[i];
    int end = offs[i + 1];

    f32x4 accL = (f32x4){0.f, 0.f, 0.f, 0.f};
    f32x4 accH = (f32x4){0.f, 0.f, 0.f, 0.f};

    // stage first 8 edges (groups: edges e+g and e+4+g)
    int   iA = csr_src[e + g],     iB = csr_src[e + 4 + g];
    float wA = csr_val[e + g],     wB = csr_val[e + 4 + g];
    h16x8 vA = *(const h16x8*)(cur + (size_t)iA * 128 + fl);
    h16x8 vB = *(const h16x8*)(cur + (size_t)iB * 128 + fl);

    for (e += 8; e < end; e += 8) {
        int   iA2 = csr_src[e + g],     iB2 = csr_src[e + 4 + g];
        float wA2 = csr_val[e + g],     wB2 = csr_val[e + 4 + g];
        h16x8 vA2 = *(const h16x8*)(cur + (size_t)iA2 * 128 + fl);
        h16x8 vB2 = *(const h16x8*)(cur + (size_t)iB2 * 128 + fl);
#pragma unroll
        for (int j = 0; j < 4; ++j) {
            accL[j] = fmaf(wA, (float)vA[j],     accL[j]);
            accH[j] = fmaf(wA, (float)vA[4 + j], accH[j]);
            accL[j] = fmaf(wB, (float)vB[j],     accL[j]);
            accH[j] = fmaf(wB, (float)vB[4 + j], accH[j]);
        }
        wA = wA2; wB = wB2; vA = vA2; vB = vB2;
    }
#pragma unroll
    for (int j = 0; j < 4; ++j) {
        accL[j] = fmaf(wA, (float)vA[j],     accL[j]);
        accH[j] = fmaf(wA, (float)vA[4 + j], accH[j]);
        accL[j] = fmaf(wB, (float)vB[j],     accL[j]);
        accH[j] = fmaf(wB, (float)vB[4 + j], accH[j]);
    }

    // combine the four group partial sums (butterfly)
#pragma unroll
    for (int j = 0; j < 4; ++j) {
        accL[j] += __shfl_xor(accL[j], 16);
        accL[j] += __shfl_xor(accL[j], 32);
        accH[j] += __shfl_xor(accH[j], 16);
        accH[j] += __shfl_xor(accH[j], 32);
    }

    if (lane < 16) {
        h16x8 hv = *(const h16x8*)(h0 + (size_t)i * 128 + fl);
        float o[8];
#pragma unroll
        for (int j = 0; j < 4; ++j) {
            o[j]     = ALPHA_F * (float)hv[j]     + (1.f - ALPHA_F) * accL[j];
            o[4 + j] = ALPHA_F * (float)hv[4 + j] + (1.f - ALPHA_F) * accH[j];
        }
        if (fout) {
            f32x4 o0, o1;
#pragma unroll
            for (int j = 0; j < 4; ++j) { o0[j] = o[j]; o1[j] = o[4 + j]; }
            *(f32x4*)(fout + (size_t)i * 128 + fl)     = o0;
            *(f32x4*)(fout + (size_t)i * 128 + fl + 4) = o1;
        } else {
            h16x8 o16;
#pragma unroll
            for (int j = 0; j < 8; ++j) o16[j] = (_Float16)o[j];
            *(h16x8*)(nxt + (size_t)i * 128 + fl) = o16;
        }
    }
}

// ---------------------------------------------------------------------------
static inline size_t align_up(size_t x) { return (x + 255) & ~(size_t)255; }

extern "C" void kernel_launch(void* const* d_in, const int* in_sizes, int n_in,
                              void* d_out, int out_size, void* d_ws, size_t ws_size,
                              hipStream_t stream)
{
    const float* x   = (const float*)d_in[0];
    const int*   ei  = (const int*)d_in[1];
    const float* W1  = (const float*)d_in[2];
    const float* b1  = (const float*)d_in[3];
    const float* g1  = (const float*)d_in[4];
    const float* be1 = (const float*)d_in[5];
    const float* m1  = (const float*)d_in[6];
    const float* v1  = (const float*)d_in[7];
    const float* W2  = (const float*)d_in[8];
    const float* b2  = (const float*)d_in[9];
    const float* g2  = (const float*)d_in[10];
    const float* be2 = (const float*)d_in[11];
    const float* m2  = (const float*)d_in[12];
    const float* v2  = (const float*)d_in[13];

    const int N = in_sizes[0] / 512;   // 50000
    const int E = in_sizes[1] / 2;     // 800000
    const int* src = ei;
    const int* dst = ei + E;
    const int CSR_CAP = E + 8 * N;
    const int NB = (N + 1023) / 1024;  // 49

    char* ws = (char*)d_ws;
    size_t off = 0;
    _Float16* hAh = (_Float16*)(ws + off); off += align_up((size_t)N * 128 * 2);
    _Float16* h0h = (_Float16*)(ws + off); off += align_up((size_t)N * 128 * 2);
    _Float16* p0  = (_Float16*)(ws + off); off += align_up((size_t)N * 128 * 2);
    _Float16* p1  = (_Float16*)(ws + off); off += align_up((size_t)N * 128 * 2);
    int*    deg  = (int*)(ws + off);    off += align_up((size_t)N * 4);
    float*  dinv = (float*)(ws + off);  off += align_up((size_t)N * 4);
    int*    offs = (int*)(ws + off);    off += align_up((size_t)(N + 1) * 4);
    int*    curs = (int*)(ws + off);    off += align_up((size_t)N * 4);
    int*    bsum = (int*)(ws + off);    off += align_up((size_t)256 * 4);
    int*    csrs = (int*)(ws + off);    off += align_up((size_t)CSR_CAP * 4);
    float*  csrv = (float*)(ws + off);  off += align_up((size_t)CSR_CAP * 4);
    bf16_t* w1h  = (bf16_t*)(ws + off); off += align_up((size_t)512 * 128 * 2);
    bf16_t* w1l  = (bf16_t*)(ws + off); off += align_up((size_t)512 * 128 * 2);
    bf16_t* w2h  = (bf16_t*)(ws + off); off += align_up((size_t)128 * 128 * 2);
    bf16_t* w2l  = (bf16_t*)(ws + off); off += align_up((size_t)128 * 128 * 2);

    // --- graph preprocessing ---
    hipMemsetAsync(deg, 0, (size_t)N * 4, stream);
    count_deg<<<(E + 255) / 256, 256, 0, stream>>>(dst, E, deg);
    scan_block_sums<<<NB, 256, 0, stream>>>(deg, bsum, N);
    scan_offsets<<<NB, 256, 0, stream>>>(deg, bsum, offs, curs, N, NB);
    compute_dinv<<<(N + 255) / 256, 256, 0, stream>>>(deg, dinv, N);
    scatter_csr<<<(E + 255) / 256, 256, 0, stream>>>(src, dst, E, dinv, curs, csrs, csrv);
    fill_self_pad<<<(N + 255) / 256, 256, 0, stream>>>(offs, deg, dinv, csrs, csrv, N);

    // --- weights -> transposed bf16 hi/lo ---
    convert_wt<<<(512 * 128 + 255) / 256, 256, 0, stream>>>(W1, w1h, w1l, 512);
    convert_wt<<<(128 * 128 + 255) / 256, 256, 0, stream>>>(W2, w2h, w2l, 128);

    // --- MLP: hAh = BN1(relu(x@W1+b1)) fp16; h0h = BN2(hAh@W2+b2) fp16 ---
    gemm_mfma_bn<false, true><<<(N + 63) / 64, 256, 0, stream>>>(
        x, w1h, w1l, b1, g1, be1, m1, v1, hAh, N, 512, 1);
    gemm_mfma_bn<true, true><<<(N + 63) / 64, 256, 0, stream>>>(
        hAh, w2h, w2l, b2, g2, be2, m2, v2, h0h, N, 128, 0);

    // --- 10 propagation steps (fp16 ping-pong); step 10 writes fp32 d_out ---
    const _Float16* cur = h0h;
    for (int k = 0; k < 10; ++k) {
        _Float16* nxt = (k & 1) ? p1 : p0;
        float* fo = (k == 9) ? (float*)d_out : nullptr;
        appnp_step<<<(N + 3) / 4, 256, 0, stream>>>(
            cur, h0h, offs, csrs, csrv, nxt, fo, N);
        cur = nxt;
    }

    (void)n_in; (void)out_size; (void)ws_size;
}